// Round 19
// baseline (74.816 us; speedup 1.0000x reference)
//
#include <hip/hip_runtime.h>

#define NT 2000000
#define NE 20000
#define NT4 (NT / 4)          // 500000, exact
#define K1_BLOCKS 2048
#define K1_WAVES (K1_BLOCKS * 4)   // 8192 waves; 8 blocks/CU resident
#define K2_BLOCKS ((NE + 255) / 256) // 79 (4 waves x 64 events each)
#define NSEG 65
#define K0_BLOCKS ((NT4 + 255) / 256)  // 1954

using half8  = __attribute__((ext_vector_type(8))) _Float16;
using half4v = __attribute__((ext_vector_type(4))) _Float16;
using f32x4  = __attribute__((ext_vector_type(4))) float;
using fvec4  = __attribute__((ext_vector_type(4))) float;

// ---------------- K0 (fused): PWL table (blocks<65) + offsets + zero s2/counter --
__global__ __launch_bounds__(256) void k0_fused(
    const int* __restrict__ seg, int* __restrict__ off, float* __restrict__ s2,
    int* __restrict__ counter,
    const float* __restrict__ w0, const float* __restrict__ b0,
    const float* __restrict__ w1, const float* __restrict__ b1,
    float* __restrict__ sorted_t, half4v* __restrict__ tabg) {
    if (blockIdx.x < NSEG) {
        __shared__ float tS[64], w0S[64], b0S[64], aS[64], cS[64];
        __shared__ int styleS[64], rankS[64];
        const int k = threadIdx.x;
        float t = 0.f; int rank = 0;
        if (k < 64) {
            const float w = w0[k], b = b0[k];
            int style;
            if (w != 0.f) { t = -b / w; style = (w > 0.f) ? 1 : 0; }
            else          { t = (b > 0.f) ? -INFINITY : INFINITY; style = 1; }
            tS[k] = t; w0S[k] = w; b0S[k] = b; styleS[k] = style;
        }
        __syncthreads();
        if (k < 64) {
            for (int i = 0; i < 64; i++) {
                const float ti = tS[i];
                rank += (ti < t || (ti == t && i < k)) ? 1 : 0;
            }
            rankS[k] = rank;
        }
        __syncthreads();
        if (k < 64) {
            if (blockIdx.x == 0) sorted_t[rank] = t;
            const int s = blockIdx.x;          // segment 0..64
            float a = 0.f, c = b1[k];          // thread k = output feature j
            for (int kk = 0; kk < 64; kk++) {
                const bool act = styleS[kk] ? (s > rankS[kk]) : (s <= rankS[kk]);
                if (act) {
                    const float wjk = w1[k * 64 + kk];
                    a = fmaf(wjk, w0S[kk], a);
                    c = fmaf(wjk, b0S[kk], c);
                }
            }
            aS[k] = a; cS[k] = c;
        }
        __syncthreads();
        if (k < 32) {
            const int s = blockIdx.x;
            tabg[s * 32 + k] = half4v{
                (_Float16)aS[2 * k],     (_Float16)cS[2 * k],
                (_Float16)aS[2 * k + 1], (_Float16)cS[2 * k + 1]};
        }
    }

    // ---- offsets scatter (all blocks) ----
    if (blockIdx.x == 0) {
        if (threadIdx.x < 64) s2[threadIdx.x] = 0.f;
        if (threadIdx.x == 64) *counter = 0;
    }
    const int g = blockIdx.x * 256 + threadIdx.x;
    if (g >= NT4) return;
    const int idx4 = g * 4;
    const int4 s = *(const int4*)(seg + idx4);
    int prev = (g == 0) ? -1 : seg[idx4 - 1];
    int vals[4] = {s.x, s.y, s.z, s.w};
#pragma unroll
    for (int k = 0; k < 4; k++) {
        const int cur = vals[k];
        if (cur != prev) {
            for (int e = prev + 1; e <= cur; ++e) off[e] = idx4 + k;
        }
        prev = cur;
    }
    if (idx4 + 3 == NT - 1) {
        for (int e = prev + 1; e <= NE; ++e) off[e] = NT;
    }
}

// ---------------- K1: phi1 via PWL table, pair-packed, STRAIGHT-LINE full blocks -
// r18 post-mortem: per-group uniform breaks = scheduling barriers; each group
// eats its own ds_read latency. Fix: full 64-particle blocks are branch-free
// (fully unrolled, no bounds) so the compiler pipelines all 32 ds_reads; only
// the <64 tail keeps the break-y form. Tripwire: FETCH ~4.6MB.
__global__ __launch_bounds__(256) void k1_phi1(
    const float* __restrict__ values, const int* __restrict__ off,
    const float* __restrict__ sorted_t, const half4v* __restrict__ gtab,
    float* __restrict__ ev) {
    __shared__ __align__(16) half4v tab[NSEG * 32];   // 16640 B
    const int tid = threadIdx.x;
    const int w = tid >> 6, l = tid & 63;
    const int l31 = l & 31;
    const bool lo32 = (l < 32);

    for (int idx = tid; idx < NSEG * 32; idx += 256) tab[idx] = gtab[idx];
    const float t_l = sorted_t[l];
    __syncthreads();

    // 2 particles: A on lanes 0-31, B on lanes 32-63; 1 ds_read_b64
    auto PROC2 = [&](int v_li, int i, int j, float2& acc) {
        const float vsA = __int_as_float(__builtin_amdgcn_readlane(v_li, i));
        const float vsB = __int_as_float(__builtin_amdgcn_readlane(v_li, j));
        const int sgA = (int)__popcll(__ballot(vsA > t_l));
        const int sgB = (int)__popcll(__ballot(vsB > t_l));
        const int sg  = lo32 ? sgA : sgB;
        const float vs = lo32 ? vsA : vsB;
        const half4v ac = tab[sg * 32 + l31];
        acc.x += fmaxf(fmaf((float)ac[0], vs, (float)ac[1]), 0.f);
        acc.y += fmaxf(fmaf((float)ac[2], vs, (float)ac[3]), 0.f);
    };
    auto PROC1 = [&](int v_li, int i, float2& acc) {
        const float vsA = __int_as_float(__builtin_amdgcn_readlane(v_li, i));
        const int sgA = (int)__popcll(__ballot(vsA > t_l));
        const half4v ac = tab[sgA * 32 + l31];
        const float x = fmaxf(fmaf((float)ac[0], vsA, (float)ac[1]), 0.f);
        const float y = fmaxf(fmaf((float)ac[2], vsA, (float)ac[3]), 0.f);
        acc.x += lo32 ? x : 0.f;
        acc.y += lo32 ? y : 0.f;
    };

    const int wid = blockIdx.x * 4 + w;
    for (int e = wid; e < NE; e += K1_WAVES) {
        const int ps = off[e], pe = off[e + 1];
        float2 p0 = {0.f, 0.f}, p1 = {0.f, 0.f};
        float2 p2 = {0.f, 0.f}, p3 = {0.f, 0.f};

        int base = ps;
        // ---- FULL blocks: branch-free body, 32 ds_reads pipelined ----
        for (; base + 64 <= pe; base += 64) {
            const int v_li = __float_as_int(values[base + l]);
#pragma unroll
            for (int g = 0; g < 8; ++g) {
                PROC2(v_li, 8 * g,     8 * g + 1, p0);
                PROC2(v_li, 8 * g + 2, 8 * g + 3, p1);
                PROC2(v_li, 8 * g + 4, 8 * g + 5, p2);
                PROC2(v_li, 8 * g + 6, 8 * g + 7, p3);
            }
        }
        // ---- tail block (0..63 particles), break-y ----
        const int cnt = pe - base;
        if (cnt > 0) {
            const float v_l = (base + l < pe) ? values[base + l] : 0.f;
            const int v_li = __float_as_int(v_l);
            const int fullg = cnt >> 3;
#pragma unroll
            for (int g = 0; g < 7; ++g) {
                if (g >= fullg) break;                // uniform break
                PROC2(v_li, 8 * g,     8 * g + 1, p0);
                PROC2(v_li, 8 * g + 2, 8 * g + 3, p1);
                PROC2(v_li, 8 * g + 4, 8 * g + 5, p2);
                PROC2(v_li, 8 * g + 6, 8 * g + 7, p3);
            }
            int tb = fullg * 8;                       // remainder 0..7
            if (tb + 1 < cnt) { PROC2(v_li, tb, tb + 1, p0); tb += 2; }
            if (tb + 1 < cnt) { PROC2(v_li, tb, tb + 1, p1); tb += 2; }
            if (tb + 1 < cnt) { PROC2(v_li, tb, tb + 1, p2); tb += 2; }
            if (tb < cnt)     { PROC1(v_li, tb, p3); }
        }

        // fold B-half into A-half, store float2 per lane (feature order kept)
        float s0 = (p0.x + p1.x) + (p2.x + p3.x);
        float s1 = (p0.y + p1.y) + (p2.y + p3.y);
        s0 += __shfl_xor(s0, 32);
        s1 += __shfl_xor(s1, 32);
        if (lo32)
            *(float2*)(ev + (size_t)e * 64 + 2 * l31) = make_float2(s0, s1);
    }
}

// ------- K2: rho1+o1+phi2 (5 layers) with LDS-STAGED f16 weights, 4 waves/block --
// r18 decomposition: k2 ~15-17us = 313 single-wave blocks each latency-bound
// pulling 80KB weights through L2. Now: 79 blocks x 256 threads; weights
// staged ONCE per block into LDS (stride-72, 16B-aligned b128 reads); per-wave
// xt slabs; rho2+out+log_softmax tail fused on the last block.
__global__ __launch_bounds__(256) void k2_events(
    const float* __restrict__ ev,
    const float* __restrict__ W0, const float* __restrict__ B0,
    const float* __restrict__ W1, const float* __restrict__ B1,
    const float* __restrict__ W2, const float* __restrict__ B2,
    const float* __restrict__ W3, const float* __restrict__ B3,
    const float* __restrict__ W4, const float* __restrict__ B4,
    float* __restrict__ s2, int* __restrict__ counter,
    const float* __restrict__ R0, const float* __restrict__ Rb0,
    const float* __restrict__ R1, const float* __restrict__ Rb1,
    const float* __restrict__ OW, const float* __restrict__ OB,
    float* __restrict__ out) {
    __shared__ __align__(16) _Float16 wlds[5 * 64 * 72];   // 46080 B
    __shared__ __align__(16) _Float16 xt[4 * 64 * 72];     // 36864 B
    const int tid = threadIdx.x;
    const int w   = tid >> 6;
    const int l   = tid & 63;
    const int l15 = l & 15;
    const int l4  = l >> 4;
    const int ebase = blockIdx.x * 256 + w * 64;

    // ---- stage all 5 weight matrices as f16 into LDS (stride 72) ----
    {
        const float* Wsrc[5] = {W0, W1, W2, W3, W4};
#pragma unroll
        for (int L = 0; L < 5; L++) {
            const float* Wp = Wsrc[L];        // L compile-time (unrolled)
            for (int idx = tid; idx < 4096; idx += 256) {
                const int row = idx >> 6, col = idx & 63;
                wlds[(L * 64 + row) * 72 + col] = (_Float16)Wp[idx];
            }
        }
    }
    __syncthreads();

    const float* Bs[5] = {B0, B1, B2, B3, B4};
    _Float16* xtw = xt + w * 64 * 72;

    // A fragments from ev (f32 -> f16), masked for e >= NE
    half8 A[4][2];
#pragma unroll
    for (int pf = 0; pf < 4; pf++) {
        const int e = ebase + pf * 16 + l15;
#pragma unroll
        for (int kf = 0; kf < 2; kf++) {
            half8 a;
            if (e < NE) {
                const float* p = ev + (size_t)e * 64 + kf * 32 + l4 * 8;
                fvec4 x = *(const fvec4*)p;
                fvec4 y = *(const fvec4*)(p + 4);
#pragma unroll
                for (int e2 = 0; e2 < 4; e2++) {
                    a[e2]     = (_Float16)x[e2];
                    a[e2 + 4] = (_Float16)y[e2];
                }
            } else {
#pragma unroll
                for (int e2 = 0; e2 < 8; e2++) a[e2] = (_Float16)0.f;
            }
            A[pf][kf] = a;
        }
    }

#pragma unroll
    for (int L = 0; L < 5; L++) {
        half8 Bh[2][4];
#pragma unroll
        for (int kf = 0; kf < 2; kf++)
#pragma unroll
            for (int jf = 0; jf < 4; jf++)
                Bh[kf][jf] = *(const half8*)(wlds +
                    (L * 64 + jf * 16 + l15) * 72 + kf * 32 + l4 * 8);

        f32x4 acc[4][4];
#pragma unroll
        for (int jf = 0; jf < 4; jf++) {
            const float bj = Bs[L][jf * 16 + l15];
#pragma unroll
            for (int pf = 0; pf < 4; pf++)
#pragma unroll
                for (int r = 0; r < 4; r++) acc[pf][jf][r] = bj;
        }
#pragma unroll
        for (int kf = 0; kf < 2; kf++)
#pragma unroll
            for (int pf = 0; pf < 4; pf++)
#pragma unroll
                for (int jf = 0; jf < 4; jf++)
                    acc[pf][jf] = __builtin_amdgcn_mfma_f32_16x16x32_f16(
                        A[pf][kf], Bh[kf][jf], acc[pf][jf], 0, 0, 0);

        if (L < 4) {
#pragma unroll
            for (int pf = 0; pf < 4; pf++)
#pragma unroll
                for (int jf = 0; jf < 4; jf++) {
                    const int j = jf * 16 + l15;
#pragma unroll
                    for (int r = 0; r < 4; r++)
                        xtw[(pf * 16 + l4 * 4 + r) * 72 + j] =
                            (_Float16)fmaxf(acc[pf][jf][r], 0.f);
                }
#pragma unroll
            for (int pf = 0; pf < 4; pf++)
#pragma unroll
                for (int kf = 0; kf < 2; kf++)
                    A[pf][kf] = *(const half8*)(xtw + (pf * 16 + l15) * 72 +
                                                kf * 32 + l4 * 8);
        } else {
            float sj[4];
#pragma unroll
            for (int jf = 0; jf < 4; jf++) {
                float s = 0.f;
#pragma unroll
                for (int pf = 0; pf < 4; pf++)
#pragma unroll
                    for (int r = 0; r < 4; r++) {
                        const int e = ebase + pf * 16 + l4 * 4 + r;
                        float v = fmaxf(acc[pf][jf][r], 0.f);
                        s += (e < NE) ? v : 0.f;
                    }
                s += __shfl_xor(s, 16);
                s += __shfl_xor(s, 32);
                sj[jf] = s;
            }
            float v = (l4 == 0) ? sj[0] : (l4 == 1) ? sj[1]
                    : (l4 == 2) ? sj[2] : sj[3];
            atomicAdd(s2 + l, v);
        }
    }

    // ---- fused rho2 + output + log_softmax: last block to finish does it ----
    __shared__ int is_last;
    __threadfence();
    __syncthreads();                       // all 4 waves' atomics issued
    if (tid == 0) {
        const int c = atomicAdd(counter, 1);
        is_last = (c == (int)gridDim.x - 1);
    }
    __syncthreads();
    if (!is_last) return;

    __shared__ __align__(16) float xb[64];
    __shared__ __align__(16) float yb[64];
    __shared__ float ob[10];

    if (tid < 64) xb[tid] = atomicAdd(s2 + tid, 0.f);   // coherent read
    __syncthreads();

    if (tid < 64) {
        float a0 = Rb0[tid];
#pragma unroll
        for (int k = 0; k < 16; k++) {
            fvec4 wv = *(const fvec4*)(R0 + tid * 64 + k * 4);
            fvec4 xv = *(const fvec4*)(xb + k * 4);
            a0 += wv[0] * xv[0] + wv[1] * xv[1] + wv[2] * xv[2] + wv[3] * xv[3];
        }
        yb[tid] = fmaxf(a0, 0.f);
    }
    __syncthreads();

    float b_ = 0.f;
    if (tid < 64) {
        b_ = Rb1[tid];
#pragma unroll
        for (int k = 0; k < 16; k++) {
            fvec4 wv = *(const fvec4*)(R1 + tid * 64 + k * 4);
            fvec4 xv = *(const fvec4*)(yb + k * 4);
            b_ += wv[0] * xv[0] + wv[1] * xv[1] + wv[2] * xv[2] + wv[3] * xv[3];
        }
    }
    __syncthreads();
    if (tid < 64) xb[tid] = fmaxf(b_, 0.f);
    __syncthreads();

    if (tid < 10) {
        float o = OB[tid];
#pragma unroll
        for (int k = 0; k < 16; k++) {
            fvec4 wv = *(const fvec4*)(OW + tid * 64 + k * 4);
            fvec4 xv = *(const fvec4*)(xb + k * 4);
            o += wv[0] * xv[0] + wv[1] * xv[1] + wv[2] * xv[2] + wv[3] * xv[3];
        }
        ob[tid] = o;
    }
    __syncthreads();
    if (tid == 0) {
        float m = ob[0];
#pragma unroll
        for (int i = 1; i < 10; i++) m = fmaxf(m, ob[i]);
        float sum = 0.f;
#pragma unroll
        for (int i = 0; i < 10; i++) sum = sum + expf(ob[i] - m);
        float ls = logf(sum);
#pragma unroll
        for (int i = 0; i < 10; i++) out[i] = ob[i] - m - ls;
    }
}

extern "C" void kernel_launch(void* const* d_in, const int* in_sizes, int n_in,
                              void* d_out, int out_size, void* d_ws, size_t ws_size,
                              hipStream_t stream) {
    const float* values = (const float*)d_in[0];
    const int*   seg    = (const int*)d_in[1];
    const float* p1w0 = (const float*)d_in[2],  *p1b0 = (const float*)d_in[3];
    const float* p1w1 = (const float*)d_in[4],  *p1b1 = (const float*)d_in[5];
    const float* r1w0 = (const float*)d_in[6],  *r1b0 = (const float*)d_in[7];
    const float* r1w1 = (const float*)d_in[8],  *r1b1 = (const float*)d_in[9];
    const float* o1w  = (const float*)d_in[10], *o1b  = (const float*)d_in[11];
    const float* p2w0 = (const float*)d_in[12], *p2b0 = (const float*)d_in[13];
    const float* p2w1 = (const float*)d_in[14], *p2b1 = (const float*)d_in[15];
    const float* r2w0 = (const float*)d_in[16], *r2b0 = (const float*)d_in[17];
    const float* r2w1 = (const float*)d_in[18], *r2b1 = (const float*)d_in[19];
    const float* o2w  = (const float*)d_in[20], *o2b  = (const float*)d_in[21];

    float*  ev       = (float*)d_ws;                 // [NE][64]
    float*  s2       = ev + (size_t)NE * 64;         // [64]
    int*    off      = (int*)(s2 + 64);              // [NE+1]
    int*    counter  = off + (NE + 1);               // [1]
    float*  sorted_t = (float*)(counter + 1);        // [64]
    half4v* tabg     = (half4v*)(sorted_t + 64);     // [65*32] x 8B

    hipLaunchKernelGGL(k0_fused, dim3(K0_BLOCKS), dim3(256), 0, stream,
                       seg, off, s2, counter,
                       p1w0, p1b0, p1w1, p1b1, sorted_t, tabg);
    hipLaunchKernelGGL(k1_phi1, dim3(K1_BLOCKS), dim3(256), 0, stream,
                       values, off, sorted_t, tabg, ev);
    hipLaunchKernelGGL(k2_events, dim3(K2_BLOCKS), dim3(256), 0, stream,
                       ev, r1w0, r1b0, r1w1, r1b1, o1w, o1b,
                       p2w0, p2b0, p2w1, p2b1, s2, counter,
                       r2w0, r2b0, r2w1, r2b1, o2w, o2b, (float*)d_out);
}

// Round 20
// 68.264 us; speedup vs baseline: 1.0960x; 1.0960x over previous
//
#include <hip/hip_runtime.h>

#define NT 2000000
#define NE 20000
#define NT4 (NT / 4)          // 500000, exact
#define K1_BLOCKS 1024
#define K1_WAVES (K1_BLOCKS * 4)   // 4096 -> 4.88 events/wave (balanced)
#define K2_BLOCKS ((NE + 63) / 64) // 313

using bf16x8 = __attribute__((ext_vector_type(8))) __bf16;
using half8  = __attribute__((ext_vector_type(8))) _Float16;
using half2v = __attribute__((ext_vector_type(2))) _Float16;
using f32x4  = __attribute__((ext_vector_type(4))) float;
using f32x2  = __attribute__((ext_vector_type(2))) float;
using fvec4  = __attribute__((ext_vector_type(4))) float;

// 8 consecutive f32 -> f16x8
__device__ __forceinline__ half8 load_h8(const float* __restrict__ p) {
    fvec4 a = *(const fvec4*)p;
    fvec4 b = *(const fvec4*)(p + 4);
    half8 r;
#pragma unroll
    for (int e = 0; e < 4; e++) {
        r[e]     = (_Float16)a[e];
        r[e + 4] = (_Float16)b[e];
    }
    return r;
}

// ---------------- K0: event offsets via boundary scatter + zero s2/counter -------
__global__ __launch_bounds__(256) void k0_offsets(
    const int* __restrict__ seg, int* __restrict__ off, float* __restrict__ s2,
    int* __restrict__ counter) {
    if (blockIdx.x == 0) {
        if (threadIdx.x < 64) s2[threadIdx.x] = 0.f;
        if (threadIdx.x == 64) *counter = 0;
    }
    const int g = blockIdx.x * 256 + threadIdx.x;
    if (g >= NT4) return;
    const int idx4 = g * 4;
    const int4 s = *(const int4*)(seg + idx4);
    int prev = (g == 0) ? -1 : seg[idx4 - 1];
    int vals[4] = {s.x, s.y, s.z, s.w};
#pragma unroll
    for (int k = 0; k < 4; k++) {
        const int cur = vals[k];
        if (cur != prev) {
            for (int e = prev + 1; e <= cur; ++e) off[e] = idx4 + k;
        }
        prev = cur;
    }
    if (idx4 + 3 == NT - 1) {
        for (int e = prev + 1; e <= NE; ++e) off[e] = NT;
    }
}

// ---------------- K1: fused phi1 (2 layers) + per-event sum, WAVE PER EVENT ------
// QUAD independent chains (r13 dual gave 46->42; chains are the only lever
// that has moved this kernel). (256,3): cap 170 >> est. demand ~130 -> no
// spill. Tripwire: FETCH_SIZE ~4.6MB (scratch spill -> revert to r14/dual).
__global__ __launch_bounds__(256, 3) void k1_phi1(
    const float* __restrict__ values, const int* __restrict__ off,
    const float* __restrict__ w0, const float* __restrict__ b0,
    const float* __restrict__ w1, const float* __restrict__ b1,
    float* __restrict__ ev) {
    const int tid = threadIdx.x;
    const int w   = tid >> 6;
    const int l   = tid & 63;
    const int l15 = l & 15;
    const int l4  = l >> 4;

    // B fragments for W1 (f16): lane holds col j=16jf+l15, k = 32kf+8*l4+e
    half8 Bh[2][4];
#pragma unroll
    for (int kf = 0; kf < 2; kf++)
#pragma unroll
        for (int jf = 0; jf < 4; jf++)
            Bh[kf][jf] = load_h8(w1 + (jf * 16 + l15) * 64 + kf * 32 + l4 * 8);

    // layer-1 weights as f16 pairs -> v_pk_fma_f16 in the A-build
    half2v w0h[2][4], b0h[2][4];
#pragma unroll
    for (int kf = 0; kf < 2; kf++) {
        const int kb = kf * 32 + l4 * 8;
#pragma unroll
        for (int e2 = 0; e2 < 4; e2++) {
            f32x2 wp = *(const f32x2*)(w0 + kb + 2 * e2);
            f32x2 bp = *(const f32x2*)(b0 + kb + 2 * e2);
            w0h[kf][e2] = half2v{(_Float16)wp[0], (_Float16)wp[1]};
            b0h[kf][e2] = half2v{(_Float16)bp[0], (_Float16)bp[1]};
        }
    }
    // bias as ready-made C fragment
    f32x4 biasC[4];
#pragma unroll
    for (int jf = 0; jf < 4; jf++) {
        const float bj = b1[jf * 16 + l15];
#pragma unroll
        for (int r = 0; r < 4; r++) biasC[jf][r] = bj;
    }

    // h1 = relu(v*w0+b0) in packed f16, directly in A-fragment layout
    auto buildA = [&](_Float16 v, half8& A0, half8& A1) {
        const half2v vv = {v, v};
#pragma unroll
        for (int e2 = 0; e2 < 4; e2++) {
            half2v h0 = vv * w0h[0][e2] + b0h[0][e2];   // v_pk_fma_f16
            half2v h1 = vv * w0h[1][e2] + b0h[1][e2];
            const _Float16 z = (_Float16)0.f;
            A0[2 * e2]     = h0[0] > z ? h0[0] : z;
            A0[2 * e2 + 1] = h0[1] > z ? h0[1] : z;
            A1[2 * e2]     = h1[0] > z ? h1[0] : z;
            A1[2 * e2 + 1] = h1[1] > z ? h1[1] : z;
        }
    };
    // 2-MFMA chain per jf, relu'd and folded into running partials
    auto chain = [&](const half8& A0, const half8& A1, float* sj) {
#pragma unroll
        for (int jf = 0; jf < 4; jf++) {
            f32x4 tt = __builtin_amdgcn_mfma_f32_16x16x32_f16(
                A0, Bh[0][jf], biasC[jf], 0, 0, 0);
            tt = __builtin_amdgcn_mfma_f32_16x16x32_f16(
                A1, Bh[1][jf], tt, 0, 0, 0);
            sj[jf] += (fmaxf(tt[0], 0.f) + fmaxf(tt[1], 0.f)) +
                      (fmaxf(tt[2], 0.f) + fmaxf(tt[3], 0.f));
        }
    };
    auto chainTail = [&](const half8& A0, const half8& A1, float* sj, int rem) {
#pragma unroll
        for (int jf = 0; jf < 4; jf++) {
            f32x4 tt = __builtin_amdgcn_mfma_f32_16x16x32_f16(
                A0, Bh[0][jf], biasC[jf], 0, 0, 0);
            tt = __builtin_amdgcn_mfma_f32_16x16x32_f16(
                A1, Bh[1][jf], tt, 0, 0, 0);
            float s = 0.f;
#pragma unroll
            for (int r = 0; r < 4; r++) {
                const bool ok = (l4 * 4 + r) < rem;
                s += ok ? fmaxf(tt[r], 0.f) : 0.f;
            }
            sj[jf] += s;
        }
    };

    // 2-step butterfly: lane l ends holding full column sum of feature j==l
    const bool bit0 = (l & 16) != 0;
    const bool bit1 = (l & 32) != 0;
    auto reduce4 = [&](const float sj[4]) -> float {
        float send01 = bit0 ? sj[0] : sj[1];
        float keep01 = bit0 ? sj[1] : sj[0];
        float c01 = keep01 + __shfl_xor(send01, 16);
        float send23 = bit0 ? sj[2] : sj[3];
        float keep23 = bit0 ? sj[3] : sj[2];
        float c23 = keep23 + __shfl_xor(send23, 16);
        float send = bit1 ? c01 : c23;
        float keep = bit1 ? c23 : c01;
        return keep + __shfl_xor(send, 32);
    };

    const int wid = blockIdx.x * 4 + w;          // 4096 waves

    for (int e = wid; e < NE; e += K1_WAVES) {
        const int s = off[e];
        const int t = off[e + 1];
        const int n = t - s;
        const int nfull = n >> 4;
        const float* vp = values + s + l15;

        float sjA[4] = {0.f, 0.f, 0.f, 0.f};
        float sjB[4] = {0.f, 0.f, 0.f, 0.f};
        float sjC[4] = {0.f, 0.f, 0.f, 0.f};
        float sjD[4] = {0.f, 0.f, 0.f, 0.f};

        int b = 0;
        // QUAD independent full blocks per iteration (deep ILP; full blocks
        // need NO per-lane bounds check)
        for (; b + 4 <= nfull; b += 4) {
            const _Float16 vA = (_Float16)vp[b * 16];
            const _Float16 vB = (_Float16)vp[b * 16 + 16];
            const _Float16 vC = (_Float16)vp[b * 16 + 32];
            const _Float16 vD = (_Float16)vp[b * 16 + 48];
            half8 A0A, A1A, A0B, A1B, A0C, A1C, A0D, A1D;
            buildA(vA, A0A, A1A);
            buildA(vB, A0B, A1B);
            buildA(vC, A0C, A1C);
            buildA(vD, A0D, A1D);
            chain(A0A, A1A, sjA);
            chain(A0B, A1B, sjB);
            chain(A0C, A1C, sjC);
            chain(A0D, A1D, sjD);
        }
        // remaining 0..3 full blocks
        for (; b < nfull; ++b) {
            const _Float16 vA = (_Float16)vp[b * 16];
            half8 A0A, A1A;
            buildA(vA, A0A, A1A);
            chain(A0A, A1A, sjA);
        }
        const int rem = n & 15;
        if (rem) {                               // tail block, select-masked
            const _Float16 vA =
                (_Float16)((l15 < rem) ? vp[nfull * 16] : 0.f);
            half8 A0A, A1A;
            buildA(vA, A0A, A1A);
            chainTail(A0A, A1A, sjB, rem);
        }

        float sj[4];
#pragma unroll
        for (int jf = 0; jf < 4; jf++)
            sj[jf] = (sjA[jf] + sjB[jf]) + (sjC[jf] + sjD[jf]);
        ev[(size_t)e * 64 + l] = reduce4(sj);    // one wave owns event e
    }
}

// ------- K2: rho1+o1+phi2 (5 fused layers, f16 single) + event-sum + k3 tail -----
// (byte-identical to r14: 64-event/wave, 313 blocks, last-block rho2 tail)
__global__ __launch_bounds__(64) void k2_events(
    const float* __restrict__ ev,
    const float* __restrict__ W0, const float* __restrict__ B0,
    const float* __restrict__ W1, const float* __restrict__ B1,
    const float* __restrict__ W2, const float* __restrict__ B2,
    const float* __restrict__ W3, const float* __restrict__ B3,
    const float* __restrict__ W4, const float* __restrict__ B4,
    float* __restrict__ s2, int* __restrict__ counter,
    const float* __restrict__ R0, const float* __restrict__ Rb0,
    const float* __restrict__ R1, const float* __restrict__ Rb1,
    const float* __restrict__ OW, const float* __restrict__ OB,
    float* __restrict__ out) {
    __shared__ __align__(16) _Float16 xt[64 * 72];   // [e][k], stride 72
    const int l   = threadIdx.x;
    const int l15 = l & 15;
    const int l4  = l >> 4;
    const int ebase = blockIdx.x * 64;

    const float* Ws[5] = {W0, W1, W2, W3, W4};
    const float* Bs[5] = {B0, B1, B2, B3, B4};

    half8 A[4][2];
#pragma unroll
    for (int pf = 0; pf < 4; pf++) {
        const int e = ebase + pf * 16 + l15;
#pragma unroll
        for (int kf = 0; kf < 2; kf++) {
            half8 a;
            if (e < NE) {
                a = load_h8(ev + (size_t)e * 64 + kf * 32 + l4 * 8);
            } else {
#pragma unroll
                for (int e2 = 0; e2 < 8; e2++) a[e2] = (_Float16)0.f;
            }
            A[pf][kf] = a;
        }
    }

#pragma unroll
    for (int L = 0; L < 5; L++) {
        half8 Bh[2][4];
#pragma unroll
        for (int kf = 0; kf < 2; kf++)
#pragma unroll
            for (int jf = 0; jf < 4; jf++)
                Bh[kf][jf] = load_h8(Ws[L] + (jf * 16 + l15) * 64 +
                                     kf * 32 + l4 * 8);

        f32x4 acc[4][4];
#pragma unroll
        for (int jf = 0; jf < 4; jf++) {
            const float bj = Bs[L][jf * 16 + l15];
#pragma unroll
            for (int pf = 0; pf < 4; pf++)
#pragma unroll
                for (int r = 0; r < 4; r++) acc[pf][jf][r] = bj;
        }
#pragma unroll
        for (int kf = 0; kf < 2; kf++)
#pragma unroll
            for (int pf = 0; pf < 4; pf++)
#pragma unroll
                for (int jf = 0; jf < 4; jf++)
                    acc[pf][jf] = __builtin_amdgcn_mfma_f32_16x16x32_f16(
                        A[pf][kf], Bh[kf][jf], acc[pf][jf], 0, 0, 0);

        if (L < 4) {
#pragma unroll
            for (int pf = 0; pf < 4; pf++)
#pragma unroll
                for (int jf = 0; jf < 4; jf++) {
                    const int j = jf * 16 + l15;
#pragma unroll
                    for (int r = 0; r < 4; r++)
                        xt[(pf * 16 + l4 * 4 + r) * 72 + j] =
                            (_Float16)fmaxf(acc[pf][jf][r], 0.f);
                }
#pragma unroll
            for (int pf = 0; pf < 4; pf++)
#pragma unroll
                for (int kf = 0; kf < 2; kf++)
                    A[pf][kf] = *(const half8*)(xt + (pf * 16 + l15) * 72 +
                                                kf * 32 + l4 * 8);
        } else {
            float sj[4];
#pragma unroll
            for (int jf = 0; jf < 4; jf++) {
                float s = 0.f;
#pragma unroll
                for (int pf = 0; pf < 4; pf++)
#pragma unroll
                    for (int r = 0; r < 4; r++) {
                        const int e = ebase + pf * 16 + l4 * 4 + r;
                        float v = fmaxf(acc[pf][jf][r], 0.f);
                        s += (e < NE) ? v : 0.f;
                    }
                s += __shfl_xor(s, 16);
                s += __shfl_xor(s, 32);
                sj[jf] = s;
            }
            float v = (l4 == 0) ? sj[0] : (l4 == 1) ? sj[1]
                    : (l4 == 2) ? sj[2] : sj[3];
            atomicAdd(s2 + l, v);
        }
    }

    // ---- fused rho2 + output + log_softmax: last block to finish does it ----
    __shared__ int is_last;
    __threadfence();
    if (l == 0) {
        const int c = atomicAdd(counter, 1);
        is_last = (c == (int)gridDim.x - 1);
    }
    __syncthreads();
    if (!is_last) return;

    __shared__ __align__(16) float xb[64];
    __shared__ __align__(16) float yb[64];
    __shared__ float ob[10];

    xb[l] = atomicAdd(s2 + l, 0.f);   // coherent read (fence+counter ordered)
    __syncthreads();

    float a0 = Rb0[l];
#pragma unroll
    for (int k = 0; k < 16; k++) {
        fvec4 wv = *(const fvec4*)(R0 + l * 64 + k * 4);
        fvec4 xv = *(const fvec4*)(xb + k * 4);
        a0 += wv[0] * xv[0] + wv[1] * xv[1] + wv[2] * xv[2] + wv[3] * xv[3];
    }
    yb[l] = fmaxf(a0, 0.f);
    __syncthreads();

    float b_ = Rb1[l];
#pragma unroll
    for (int k = 0; k < 16; k++) {
        fvec4 wv = *(const fvec4*)(R1 + l * 64 + k * 4);
        fvec4 xv = *(const fvec4*)(yb + k * 4);
        b_ += wv[0] * xv[0] + wv[1] * xv[1] + wv[2] * xv[2] + wv[3] * xv[3];
    }
    __syncthreads();
    xb[l] = fmaxf(b_, 0.f);
    __syncthreads();

    if (l < 10) {
        float o = OB[l];
#pragma unroll
        for (int k = 0; k < 16; k++) {
            fvec4 wv = *(const fvec4*)(OW + l * 64 + k * 4);
            fvec4 xv = *(const fvec4*)(xb + k * 4);
            o += wv[0] * xv[0] + wv[1] * xv[1] + wv[2] * xv[2] + wv[3] * xv[3];
        }
        ob[l] = o;
    }
    __syncthreads();
    if (l == 0) {
        float m = ob[0];
#pragma unroll
        for (int i = 1; i < 10; i++) m = fmaxf(m, ob[i]);
        float sum = 0.f;
#pragma unroll
        for (int i = 0; i < 10; i++) sum = sum + expf(ob[i] - m);
        float ls = logf(sum);
#pragma unroll
        for (int i = 0; i < 10; i++) out[i] = ob[i] - m - ls;
    }
}

extern "C" void kernel_launch(void* const* d_in, const int* in_sizes, int n_in,
                              void* d_out, int out_size, void* d_ws, size_t ws_size,
                              hipStream_t stream) {
    const float* values = (const float*)d_in[0];
    const int*   seg    = (const int*)d_in[1];
    const float* p1w0 = (const float*)d_in[2],  *p1b0 = (const float*)d_in[3];
    const float* p1w1 = (const float*)d_in[4],  *p1b1 = (const float*)d_in[5];
    const float* r1w0 = (const float*)d_in[6],  *r1b0 = (const float*)d_in[7];
    const float* r1w1 = (const float*)d_in[8],  *r1b1 = (const float*)d_in[9];
    const float* o1w  = (const float*)d_in[10], *o1b  = (const float*)d_in[11];
    const float* p2w0 = (const float*)d_in[12], *p2b0 = (const float*)d_in[13];
    const float* p2w1 = (const float*)d_in[14], *p2b1 = (const float*)d_in[15];
    const float* r2w0 = (const float*)d_in[16], *r2b0 = (const float*)d_in[17];
    const float* r2w1 = (const float*)d_in[18], *r2b1 = (const float*)d_in[19];
    const float* o2w  = (const float*)d_in[20], *o2b  = (const float*)d_in[21];

    float* ev  = (float*)d_ws;                      // [NE][64]
    float* s2  = ev + (size_t)NE * 64;              // [64]
    int*   off = (int*)(s2 + 64);                   // [NE+1]
    int*   counter = off + (NE + 1);                // [1]

    hipLaunchKernelGGL(k0_offsets, dim3((NT4 + 255) / 256), dim3(256), 0, stream,
                       seg, off, s2, counter);
    hipLaunchKernelGGL(k1_phi1, dim3(K1_BLOCKS), dim3(256), 0, stream,
                       values, off, p1w0, p1b0, p1w1, p1b1, ev);
    hipLaunchKernelGGL(k2_events, dim3(K2_BLOCKS), dim3(64), 0, stream,
                       ev, r1w0, r1b0, r1w1, r1b1, o1w, o1b,
                       p2w0, p2b0, p2w1, p2b1, s2, counter,
                       r2w0, r2b0, r2w1, r2b1, o2w, o2b, (float*)d_out);
}

// Round 21
// 64.716 us; speedup vs baseline: 1.1561x; 1.0548x over previous
//
#include <hip/hip_runtime.h>

#define NT 2000000
#define NE 20000
#define NT4 (NT / 4)          // 500000, exact
#define K1_BLOCKS 1024
#define K1_WAVES (K1_BLOCKS * 4)   // 4096 -> 4.88 events/wave (balanced)
#define K2_BLOCKS ((NE + 63) / 64) // 313

using half8  = __attribute__((ext_vector_type(8))) _Float16;
using half2v = __attribute__((ext_vector_type(2))) _Float16;
using f32x4  = __attribute__((ext_vector_type(4))) float;
using f32x2  = __attribute__((ext_vector_type(2))) float;
using fvec4  = __attribute__((ext_vector_type(4))) float;

// 8 consecutive f32 -> f16x8
__device__ __forceinline__ half8 load_h8(const float* __restrict__ p) {
    fvec4 a = *(const fvec4*)p;
    fvec4 b = *(const fvec4*)(p + 4);
    half8 r;
#pragma unroll
    for (int e = 0; e < 4; e++) {
        r[e]     = (_Float16)a[e];
        r[e + 4] = (_Float16)b[e];
    }
    return r;
}

// ---------------- K0: event offsets via boundary scatter + zero s2/counter -------
__global__ __launch_bounds__(256) void k0_offsets(
    const int* __restrict__ seg, int* __restrict__ off, float* __restrict__ s2,
    int* __restrict__ counter) {
    if (blockIdx.x == 0) {
        if (threadIdx.x < 64) s2[threadIdx.x] = 0.f;
        if (threadIdx.x == 64) *counter = 0;
    }
    const int g = blockIdx.x * 256 + threadIdx.x;
    if (g >= NT4) return;
    const int idx4 = g * 4;
    const int4 s = *(const int4*)(seg + idx4);
    int prev = (g == 0) ? -1 : seg[idx4 - 1];
    int vals[4] = {s.x, s.y, s.z, s.w};
#pragma unroll
    for (int k = 0; k < 4; k++) {
        const int cur = vals[k];
        if (cur != prev) {
            for (int e = prev + 1; e <= cur; ++e) off[e] = idx4 + k;
        }
        prev = cur;
    }
    if (idx4 + 3 == NT - 1) {
        for (int e = prev + 1; e <= NE; ++e) off[e] = NT;
    }
}

// ---------------- K1: fused phi1 (2 layers) + per-event sum, WAVE PER EVENT ------
// r14 dual-chain verbatim (best measured: 42us, VGPR 64, occ 28%; r20 quad
// was neutral at lower occupancy) + s_setprio around MFMA clusters (T5:
// independent waves, no barriers -- the regime where setprio helped attn).
__global__ __launch_bounds__(256, 4) void k1_phi1(
    const float* __restrict__ values, const int* __restrict__ off,
    const float* __restrict__ w0, const float* __restrict__ b0,
    const float* __restrict__ w1, const float* __restrict__ b1,
    float* __restrict__ ev) {
    const int tid = threadIdx.x;
    const int w   = tid >> 6;
    const int l   = tid & 63;
    const int l15 = l & 15;
    const int l4  = l >> 4;

    // B fragments for W1 (f16): lane holds col j=16jf+l15, k = 32kf+8*l4+e
    half8 Bh[2][4];
#pragma unroll
    for (int kf = 0; kf < 2; kf++)
#pragma unroll
        for (int jf = 0; jf < 4; jf++)
            Bh[kf][jf] = load_h8(w1 + (jf * 16 + l15) * 64 + kf * 32 + l4 * 8);

    // layer-1 weights as f16 pairs -> v_pk_fma_f16 in the A-build
    half2v w0h[2][4], b0h[2][4];
#pragma unroll
    for (int kf = 0; kf < 2; kf++) {
        const int kb = kf * 32 + l4 * 8;
#pragma unroll
        for (int e2 = 0; e2 < 4; e2++) {
            f32x2 wp = *(const f32x2*)(w0 + kb + 2 * e2);
            f32x2 bp = *(const f32x2*)(b0 + kb + 2 * e2);
            w0h[kf][e2] = half2v{(_Float16)wp[0], (_Float16)wp[1]};
            b0h[kf][e2] = half2v{(_Float16)bp[0], (_Float16)bp[1]};
        }
    }
    // bias as ready-made C fragment
    f32x4 biasC[4];
#pragma unroll
    for (int jf = 0; jf < 4; jf++) {
        const float bj = b1[jf * 16 + l15];
#pragma unroll
        for (int r = 0; r < 4; r++) biasC[jf][r] = bj;
    }

    // h1 = relu(v*w0+b0) in packed f16, directly in A-fragment layout
    auto buildA = [&](_Float16 v, half8& A0, half8& A1) {
        const half2v vv = {v, v};
#pragma unroll
        for (int e2 = 0; e2 < 4; e2++) {
            half2v h0 = vv * w0h[0][e2] + b0h[0][e2];   // v_pk_fma_f16
            half2v h1 = vv * w0h[1][e2] + b0h[1][e2];
            const _Float16 z = (_Float16)0.f;
            A0[2 * e2]     = h0[0] > z ? h0[0] : z;
            A0[2 * e2 + 1] = h0[1] > z ? h0[1] : z;
            A1[2 * e2]     = h1[0] > z ? h1[0] : z;
            A1[2 * e2 + 1] = h1[1] > z ? h1[1] : z;
        }
    };
    // 2-MFMA chain per jf, relu'd and folded into running partials
    auto chain = [&](const half8& A0, const half8& A1, float* sj) {
        __builtin_amdgcn_s_setprio(1);
#pragma unroll
        for (int jf = 0; jf < 4; jf++) {
            f32x4 tt = __builtin_amdgcn_mfma_f32_16x16x32_f16(
                A0, Bh[0][jf], biasC[jf], 0, 0, 0);
            tt = __builtin_amdgcn_mfma_f32_16x16x32_f16(
                A1, Bh[1][jf], tt, 0, 0, 0);
            sj[jf] += (fmaxf(tt[0], 0.f) + fmaxf(tt[1], 0.f)) +
                      (fmaxf(tt[2], 0.f) + fmaxf(tt[3], 0.f));
        }
        __builtin_amdgcn_s_setprio(0);
    };
    auto chainTail = [&](const half8& A0, const half8& A1, float* sj, int rem) {
#pragma unroll
        for (int jf = 0; jf < 4; jf++) {
            f32x4 tt = __builtin_amdgcn_mfma_f32_16x16x32_f16(
                A0, Bh[0][jf], biasC[jf], 0, 0, 0);
            tt = __builtin_amdgcn_mfma_f32_16x16x32_f16(
                A1, Bh[1][jf], tt, 0, 0, 0);
            float s = 0.f;
#pragma unroll
            for (int r = 0; r < 4; r++) {
                const bool ok = (l4 * 4 + r) < rem;
                s += ok ? fmaxf(tt[r], 0.f) : 0.f;
            }
            sj[jf] += s;
        }
    };

    // 2-step butterfly: lane l ends holding full column sum of feature j==l
    const bool bit0 = (l & 16) != 0;
    const bool bit1 = (l & 32) != 0;
    auto reduce4 = [&](const float sj[4]) -> float {
        float send01 = bit0 ? sj[0] : sj[1];
        float keep01 = bit0 ? sj[1] : sj[0];
        float c01 = keep01 + __shfl_xor(send01, 16);
        float send23 = bit0 ? sj[2] : sj[3];
        float keep23 = bit0 ? sj[3] : sj[2];
        float c23 = keep23 + __shfl_xor(send23, 16);
        float send = bit1 ? c01 : c23;
        float keep = bit1 ? c23 : c01;
        return keep + __shfl_xor(send, 32);
    };

    const int wid = blockIdx.x * 4 + w;          // 4096 waves

    for (int e = wid; e < NE; e += K1_WAVES) {
        const int s = off[e];
        const int t = off[e + 1];
        const int n = t - s;
        const int nfull = n >> 4;
        const float* vp = values + s + l15;

        float sjA[4] = {0.f, 0.f, 0.f, 0.f};
        float sjB[4] = {0.f, 0.f, 0.f, 0.f};

        int b = 0;
        for (; b + 2 <= nfull; b += 2) {
            const _Float16 vA = (_Float16)vp[b * 16];
            const _Float16 vB = (_Float16)vp[b * 16 + 16];
            half8 A0A, A1A, A0B, A1B;
            buildA(vA, A0A, A1A);
            buildA(vB, A0B, A1B);
            chain(A0A, A1A, sjA);
            chain(A0B, A1B, sjB);
        }
        if (b < nfull) {
            const _Float16 vA = (_Float16)vp[b * 16];
            half8 A0A, A1A;
            buildA(vA, A0A, A1A);
            chain(A0A, A1A, sjA);
        }
        const int rem = n & 15;
        if (rem) {
            const _Float16 vA =
                (_Float16)((l15 < rem) ? vp[nfull * 16] : 0.f);
            half8 A0A, A1A;
            buildA(vA, A0A, A1A);
            chainTail(A0A, A1A, sjA, rem);
        }

        float sj[4];
#pragma unroll
        for (int jf = 0; jf < 4; jf++) sj[jf] = sjA[jf] + sjB[jf];
        ev[(size_t)e * 64 + l] = reduce4(sj);    // one wave owns event e
    }
}

// ------- K2: rho1+o1+phi2 with ALL-LAYER weight prefetch + event-sum + k3 tail ---
// r20 decomposition: k2 ~15us = 5 serial L2 round-trips per block (each
// layer's 8 loads wait ~500cy). Blocks are 1 wave (grid-limited occupancy)
// -> register budget ~512. Prefetch all 5 layers' B-frags (160 VGPR) +
// biases upfront: ONE latency exposure. Tripwire: if VGPR>450 / spill,
// FETCH balloons -> revert.
__global__ __launch_bounds__(64) void k2_events(
    const float* __restrict__ ev,
    const float* __restrict__ W0, const float* __restrict__ B0,
    const float* __restrict__ W1, const float* __restrict__ B1,
    const float* __restrict__ W2, const float* __restrict__ B2,
    const float* __restrict__ W3, const float* __restrict__ B3,
    const float* __restrict__ W4, const float* __restrict__ B4,
    float* __restrict__ s2, int* __restrict__ counter,
    const float* __restrict__ R0, const float* __restrict__ Rb0,
    const float* __restrict__ R1, const float* __restrict__ Rb1,
    const float* __restrict__ OW, const float* __restrict__ OB,
    float* __restrict__ out) {
    __shared__ __align__(16) _Float16 xt[64 * 72];   // [e][k], stride 72
    const int l   = threadIdx.x;
    const int l15 = l & 15;
    const int l4  = l >> 4;
    const int ebase = blockIdx.x * 64;

    const float* Ws[5] = {W0, W1, W2, W3, W4};
    const float* Bs[5] = {B0, B1, B2, B3, B4};

    // ---- prefetch ALL layers' B fragments + biases (one latency exposure) ----
    half8 Bh[5][2][4];
#pragma unroll
    for (int L = 0; L < 5; L++)
#pragma unroll
        for (int kf = 0; kf < 2; kf++)
#pragma unroll
            for (int jf = 0; jf < 4; jf++)
                Bh[L][kf][jf] = load_h8(Ws[L] + (jf * 16 + l15) * 64 +
                                        kf * 32 + l4 * 8);
    float bj[5][4];
#pragma unroll
    for (int L = 0; L < 5; L++)
#pragma unroll
        for (int jf = 0; jf < 4; jf++) bj[L][jf] = Bs[L][jf * 16 + l15];

    // A fragments from ev (f32 -> f16), masked for e >= NE
    half8 A[4][2];
#pragma unroll
    for (int pf = 0; pf < 4; pf++) {
        const int e = ebase + pf * 16 + l15;
#pragma unroll
        for (int kf = 0; kf < 2; kf++) {
            half8 a;
            if (e < NE) {
                a = load_h8(ev + (size_t)e * 64 + kf * 32 + l4 * 8);
            } else {
#pragma unroll
                for (int e2 = 0; e2 < 8; e2++) a[e2] = (_Float16)0.f;
            }
            A[pf][kf] = a;
        }
    }

#pragma unroll
    for (int L = 0; L < 5; L++) {
        f32x4 acc[4][4];
#pragma unroll
        for (int jf = 0; jf < 4; jf++) {
#pragma unroll
            for (int pf = 0; pf < 4; pf++)
#pragma unroll
                for (int r = 0; r < 4; r++) acc[pf][jf][r] = bj[L][jf];
        }
#pragma unroll
        for (int kf = 0; kf < 2; kf++)
#pragma unroll
            for (int pf = 0; pf < 4; pf++)
#pragma unroll
                for (int jf = 0; jf < 4; jf++)
                    acc[pf][jf] = __builtin_amdgcn_mfma_f32_16x16x32_f16(
                        A[pf][kf], Bh[L][kf][jf], acc[pf][jf], 0, 0, 0);

        if (L < 4) {
            // relu -> LDS [e][j] f16, reload as next layer's A-frags
#pragma unroll
            for (int pf = 0; pf < 4; pf++)
#pragma unroll
                for (int jf = 0; jf < 4; jf++) {
                    const int j = jf * 16 + l15;
#pragma unroll
                    for (int r = 0; r < 4; r++)
                        xt[(pf * 16 + l4 * 4 + r) * 72 + j] =
                            (_Float16)fmaxf(acc[pf][jf][r], 0.f);
                }
#pragma unroll
            for (int pf = 0; pf < 4; pf++)
#pragma unroll
                for (int kf = 0; kf < 2; kf++)
                    A[pf][kf] = *(const half8*)(xt + (pf * 16 + l15) * 72 +
                                                kf * 32 + l4 * 8);
        } else {
            // final phi2 layer: relu, masked sum over events, atomic into s2
            float sj[4];
#pragma unroll
            for (int jf = 0; jf < 4; jf++) {
                float s = 0.f;
#pragma unroll
                for (int pf = 0; pf < 4; pf++)
#pragma unroll
                    for (int r = 0; r < 4; r++) {
                        const int e = ebase + pf * 16 + l4 * 4 + r;
                        float v = fmaxf(acc[pf][jf][r], 0.f);
                        s += (e < NE) ? v : 0.f;
                    }
                s += __shfl_xor(s, 16);
                s += __shfl_xor(s, 32);
                sj[jf] = s;
            }
            float v = (l4 == 0) ? sj[0] : (l4 == 1) ? sj[1]
                    : (l4 == 2) ? sj[2] : sj[3];
            atomicAdd(s2 + l, v);
        }
    }

    // ---- fused rho2 + output + log_softmax: last block to finish does it ----
    __shared__ int is_last;
    __threadfence();
    if (l == 0) {
        const int c = atomicAdd(counter, 1);
        is_last = (c == (int)gridDim.x - 1);
    }
    __syncthreads();
    if (!is_last) return;

    __shared__ __align__(16) float xb[64];
    __shared__ __align__(16) float yb[64];
    __shared__ float ob[10];

    xb[l] = atomicAdd(s2 + l, 0.f);   // coherent read (fence+counter ordered)
    __syncthreads();

    float a0 = Rb0[l];
#pragma unroll
    for (int k = 0; k < 16; k++) {
        fvec4 wv = *(const fvec4*)(R0 + l * 64 + k * 4);
        fvec4 xv = *(const fvec4*)(xb + k * 4);
        a0 += wv[0] * xv[0] + wv[1] * xv[1] + wv[2] * xv[2] + wv[3] * xv[3];
    }
    yb[l] = fmaxf(a0, 0.f);
    __syncthreads();

    float b_ = Rb1[l];
#pragma unroll
    for (int k = 0; k < 16; k++) {
        fvec4 wv = *(const fvec4*)(R1 + l * 64 + k * 4);
        fvec4 xv = *(const fvec4*)(yb + k * 4);
        b_ += wv[0] * xv[0] + wv[1] * xv[1] + wv[2] * xv[2] + wv[3] * xv[3];
    }
    __syncthreads();
    xb[l] = fmaxf(b_, 0.f);
    __syncthreads();

    if (l < 10) {
        float o = OB[l];
#pragma unroll
        for (int k = 0; k < 16; k++) {
            fvec4 wv = *(const fvec4*)(OW + l * 64 + k * 4);
            fvec4 xv = *(const fvec4*)(xb + k * 4);
            o += wv[0] * xv[0] + wv[1] * xv[1] + wv[2] * xv[2] + wv[3] * xv[3];
        }
        ob[l] = o;
    }
    __syncthreads();
    if (l == 0) {
        float m = ob[0];
#pragma unroll
        for (int i = 1; i < 10; i++) m = fmaxf(m, ob[i]);
        float sum = 0.f;
#pragma unroll
        for (int i = 0; i < 10; i++) sum = sum + expf(ob[i] - m);
        float ls = logf(sum);
#pragma unroll
        for (int i = 0; i < 10; i++) out[i] = ob[i] - m - ls;
    }
}

extern "C" void kernel_launch(void* const* d_in, const int* in_sizes, int n_in,
                              void* d_out, int out_size, void* d_ws, size_t ws_size,
                              hipStream_t stream) {
    const float* values = (const float*)d_in[0];
    const int*   seg    = (const int*)d_in[1];
    const float* p1w0 = (const float*)d_in[2],  *p1b0 = (const float*)d_in[3];
    const float* p1w1 = (const float*)d_in[4],  *p1b1 = (const float*)d_in[5];
    const float* r1w0 = (const float*)d_in[6],  *r1b0 = (const float*)d_in[7];
    const float* r1w1 = (const float*)d_in[8],  *r1b1 = (const float*)d_in[9];
    const float* o1w  = (const float*)d_in[10], *o1b  = (const float*)d_in[11];
    const float* p2w0 = (const float*)d_in[12], *p2b0 = (const float*)d_in[13];
    const float* p2w1 = (const float*)d_in[14], *p2b1 = (const float*)d_in[15];
    const float* r2w0 = (const float*)d_in[16], *r2b0 = (const float*)d_in[17];
    const float* r2w1 = (const float*)d_in[18], *r2b1 = (const float*)d_in[19];
    const float* o2w  = (const float*)d_in[20], *o2b  = (const float*)d_in[21];

    float* ev  = (float*)d_ws;                      // [NE][64]
    float* s2  = ev + (size_t)NE * 64;              // [64]
    int*   off = (int*)(s2 + 64);                   // [NE+1]
    int*   counter = off + (NE + 1);                // [1]

    hipLaunchKernelGGL(k0_offsets, dim3((NT4 + 255) / 256), dim3(256), 0, stream,
                       seg, off, s2, counter);
    hipLaunchKernelGGL(k1_phi1, dim3(K1_BLOCKS), dim3(256), 0, stream,
                       values, off, p1w0, p1b0, p1w1, p1b1, ev);
    hipLaunchKernelGGL(k2_events, dim3(K2_BLOCKS), dim3(64), 0, stream,
                       ev, r1w0, r1b0, r1w1, r1b1, o1w, o1b,
                       p2w0, p2b0, p2w1, p2b1, s2, counter,
                       r2w0, r2b0, r2w1, r2b1, o2w, o2b, (float*)d_out);
}